// Round 5
// baseline (272.350 us; speedup 1.0000x reference)
//
#include <hip/hip_runtime.h>

typedef float f32x4 __attribute__((ext_vector_type(4)));
typedef float f32x16v __attribute__((ext_vector_type(16)));
typedef __bf16 bf16x8 __attribute__((ext_vector_type(8)));

// Workspace layout (float-slot offsets; total 29383168 floats = 117.53 MB):
//   h1_hi bf16[16.78M] @ 0         h1_lo @ 8388608
//   h2_hi bf16[8.39M]  @ 16777216  h2_lo @ 20971520
//   h3    f32 [4.19M]  @ 25165824   (first 1024 floats double as c1p before conv3)
//   b2p   bf16[9216]   @ 29360128  (18 frags x 1024B, 32x32x16 B-layout)
//   b3p   bf16[36864]  @ 29364736  (72 frags x 1024B, 16x16x32 B-layout)
#define H1HI_OFF 0u
#define H1LO_OFF 8388608u
#define H2HI_OFF 16777216u
#define H2LO_OFF 20971520u
#define H3_OFF   25165824u
#define B2P_OFF  29360128u
#define B3P_OFF  29364736u

// ------------------------------------------------------------- pack_weights
// b2p frag f=t*2+p: lane l, j: oc=l&31, ic=(l>>5)*8+j              (32x32x16)
// b3p frag f=t*8+nt*2+p: lane l, j: oc=nt*16+(l&15), ic=(l>>4)*8+j (16x16x32)
// c1p frag f in {B1h,B1l,B2h,B2l}: oc=l&15, k=(l>>4)*8+j,
//   k = kxp*16 + (ky*3+ic); B1: kx=kxp; B2: kx=2 if kxp==0 else zero.
__global__ __launch_bounds__(256) void pack_weights(
    const float* __restrict__ w1, const float* __restrict__ w2,
    const float* __restrict__ w3,
    __bf16* __restrict__ b2p, __bf16* __restrict__ b3p,
    __bf16* __restrict__ c1p) {
  int i = blockIdx.x * 256 + threadIdx.x;
  if (i < 9216) {
    int f = i >> 9, r = i & 511;
    int l = r >> 3, j = r & 7;
    int t = f >> 1, p = f & 1;
    int ky = t / 3, kx = t % 3;
    int oc = l & 31, ic = ((l >> 5) << 3) + j;
    float v = w2[oc * 144 + ic * 9 + ky * 3 + kx];
    __bf16 hi = (__bf16)v;
    b2p[i] = p ? (__bf16)(v - (float)hi) : hi;
  } else if (i < 9216 + 36864) {
    int q = i - 9216;
    int f = q >> 9, r = q & 511;
    int l = r >> 3, j = r & 7;
    int t = f >> 3, nt = (f >> 1) & 3, p = f & 1;
    int ky = t / 3, kx = t % 3;
    int oc = nt * 16 + (l & 15), ic = ((l >> 4) << 3) + j;
    float v = w3[oc * 288 + ic * 9 + ky * 3 + kx];
    __bf16 hi = (__bf16)v;
    b3p[q] = p ? (__bf16)(v - (float)hi) : hi;
  } else if (i < 9216 + 36864 + 2048) {
    int q = i - (9216 + 36864);
    int f = q >> 9, r = q & 511;
    int l = r >> 3, j = r & 7;
    int oc = l & 15, k = ((l >> 4) << 3) + j;
    int kxp = k >> 4, kp = k & 15;
    int grp = f >> 1, p = f & 1;
    float v = 0.f;
    if (kp < 9 && !(grp && kxp)) {
      int ky = kp / 3, ic = kp % 3;
      int kx = grp ? 2 : kxp;
      v = w1[oc * 27 + ic * 9 + ky * 3 + kx];
    }
    __bf16 hi = (__bf16)v;
    c1p[q] = p ? (__bf16)(v - (float)hi) : hi;
  }
}

// ------------------------------------------------------------------- conv1
// MFMA 16x16x32 bf16. 1 image/block, 4 waves; wave w = output rows w*8..w*8+7.
// LDS im2col: R[y][x' 0..33][k'=ky*3+ic, 16 slots]; A-frag = one ds_read_b128.
// 2-term split (x-lo dropped): A_h*(B_h + B_l).
__global__ __launch_bounds__(256) void conv1_kernel(
    const float* __restrict__ x, const __bf16* __restrict__ c1p,
    const float* __restrict__ b1,
    __bf16* __restrict__ h1h, __bf16* __restrict__ h1l) {
  __shared__ __align__(16) __bf16 R[4 * 4352 + 8];  // +8 = zero slot @17408
  const int tid = threadIdx.x;
  const int img = blockIdx.x;
  const int w = tid >> 6, lane = tid & 63;

  for (int i = tid; i < 4354; i += 256) ((unsigned long long*)R)[i] = 0ull;
  __syncthreads();

  // Stage: R[w*4352 + (yq*34 + x')*16 + (ky*3+ic)] = bf16(x[ic][yo+ky-1][x'-1])
  {
    __bf16* Rw = R + w * 4352;
    const float* xg = x + img * 3072;
    for (int it = 0; it < 72; ++it) {
      const int yq = it / 9, e = it % 9;
      const int ky = e / 3, ic = e % 3;
      const int yi = w * 8 + yq + ky - 1;
      const int xi = lane - 1;
      if (lane < 34 && yi >= 0 && yi < 32 && xi >= 0 && xi < 32)
        Rw[(yq * 34 + lane) * 16 + e] = (__bf16)xg[ic * 1024 + yi * 32 + xi];
    }
  }

  const bf16x8 B1h = *(const bf16x8*)(c1p + 0 * 512 + lane * 8);
  const bf16x8 B1l = *(const bf16x8*)(c1p + 1 * 512 + lane * 8);
  const bf16x8 B2h = *(const bf16x8*)(c1p + 2 * 512 + lane * 8);
  const bf16x8 B2l = *(const bf16x8*)(c1p + 3 * 512 + lane * 8);
  __syncthreads();

  const int xm = lane & 15, kg = lane >> 4;
  const __bf16* Rw = R + w * 4352;
  const bf16x8* Zp = (const bf16x8*)&R[4 * 4352];
  const int oc = lane & 15, quad = lane >> 4;
  const float bias = b1[oc];

  #pragma unroll
  for (int p = 0; p < 4; ++p) {
    f32x4 acc[2][2];
    #pragma unroll
    for (int ys = 0; ys < 2; ++ys)
      #pragma unroll
      for (int xh = 0; xh < 2; ++xh)
        #pragma unroll
        for (int r = 0; r < 4; ++r) acc[ys][xh][r] = 0.f;

    #pragma unroll
    for (int ys = 0; ys < 2; ++ys) {
      const int yq = p * 2 + ys;
      #pragma unroll
      for (int xh = 0; xh < 2; ++xh) {
        const int xv = xh * 16 + xm;
        const bf16x8 A1 = *(const bf16x8*)&Rw[(yq * 34 + xv + (kg >> 1)) * 16 + (kg & 1) * 8];
        const bf16x8 A2 = (kg < 2)
            ? *(const bf16x8*)&Rw[(yq * 34 + xv + 2) * 16 + kg * 8]
            : *Zp;
        acc[ys][xh] = __builtin_amdgcn_mfma_f32_16x16x32_bf16(A1, B1h, acc[ys][xh], 0, 0, 0);
        acc[ys][xh] = __builtin_amdgcn_mfma_f32_16x16x32_bf16(A2, B2h, acc[ys][xh], 0, 0, 0);
        acc[ys][xh] = __builtin_amdgcn_mfma_f32_16x16x32_bf16(A1, B1l, acc[ys][xh], 0, 0, 0);
        acc[ys][xh] = __builtin_amdgcn_mfma_f32_16x16x32_bf16(A2, B2l, acc[ys][xh], 0, 0, 0);
      }
    }
    // Epilogue: C row = quad*4+reg = x within 16-group; col = oc.
    const int py = w * 4 + p;
    #pragma unroll
    for (int xh = 0; xh < 2; ++xh)
      #pragma unroll
      for (int xp = 0; xp < 2; ++xp) {
        const float v0 = fmaxf(acc[0][xh][xp * 2], acc[0][xh][xp * 2 + 1]);
        const float v1 = fmaxf(acc[1][xh][xp * 2], acc[1][xh][xp * 2 + 1]);
        const float v = fmaxf(fmaxf(v0, v1) + bias, 0.f);
        const int px = xh * 8 + quad * 2 + xp;
        const int idx = (img * 256 + py * 16 + px) * 16 + oc;
        const __bf16 vh = (__bf16)v;
        h1h[idx] = vh;
        h1l[idx] = (__bf16)(v - (float)vh);
      }
  }
}

// ------------------------------------------------------------------- conv2
// MFMA 32x32x16 bf16, bf16x2 split (3 terms). 1 image/block.
__global__ __launch_bounds__(256) void conv2_kernel(
    const __bf16* __restrict__ h1h, const __bf16* __restrict__ h1l,
    const __bf16* __restrict__ b2p, const float* __restrict__ b2,
    __bf16* __restrict__ h2h, __bf16* __restrict__ h2l) {
  __shared__ __align__(16) unsigned short s2[2 * 7776];
  const int tid = threadIdx.x;
  const int img = blockIdx.x;

  for (int i = tid; i < 3888; i += 256) ((unsigned long long*)s2)[i] = 0ull;
  __syncthreads();
  for (int e = tid; e < 1024; e += 256) {
    int part = e >> 9, r = e & 511;
    int ic8 = (r & 1) * 8, xx = (r >> 1) & 15, y = r >> 5;
    const __bf16* src = (part ? h1l : h1h) + img * 4096 + (y * 16 + xx) * 16 + ic8;
    uint4 v = *(const uint4*)src;
    *(uint4*)&s2[part * 7776 + (y + 1) * 432 + (xx + 1) * 24 + ic8] = v;
  }
  const int lane = tid & 63;
  bf16x8 Bf[18];
  #pragma unroll
  for (int f = 0; f < 18; ++f)
    Bf[f] = *(const bf16x8*)(b2p + f * 512 + lane * 8);
  __syncthreads();

  const int wv = tid >> 6;
  const int xm = lane & 15, yoff = (lane >> 4) & 1, kh = lane >> 5;

  f32x16v acc0, acc1;
  #pragma unroll
  for (int r = 0; r < 16; ++r) { acc0[r] = 0.f; acc1[r] = 0.f; }

  #pragma unroll
  for (int t = 0; t < 9; ++t) {
    const int ky = t / 3, kx = t % 3;
    const int col = (xm + kx) * 24 + kh * 8;
    const int row0 = (4 * wv + yoff + ky) * 432 + col;
    const int row1 = row0 + 864;
    bf16x8 a0h = *(const bf16x8*)&s2[row0];
    bf16x8 a0l = *(const bf16x8*)&s2[7776 + row0];
    bf16x8 a1h = *(const bf16x8*)&s2[row1];
    bf16x8 a1l = *(const bf16x8*)&s2[7776 + row1];
    acc0 = __builtin_amdgcn_mfma_f32_32x32x16_bf16(a0h, Bf[t * 2],     acc0, 0, 0, 0);
    acc1 = __builtin_amdgcn_mfma_f32_32x32x16_bf16(a1h, Bf[t * 2],     acc1, 0, 0, 0);
    acc0 = __builtin_amdgcn_mfma_f32_32x32x16_bf16(a0h, Bf[t * 2 + 1], acc0, 0, 0, 0);
    acc1 = __builtin_amdgcn_mfma_f32_32x32x16_bf16(a1h, Bf[t * 2 + 1], acc1, 0, 0, 0);
    acc0 = __builtin_amdgcn_mfma_f32_32x32x16_bf16(a0l, Bf[t * 2],     acc0, 0, 0, 0);
    acc1 = __builtin_amdgcn_mfma_f32_32x32x16_bf16(a1l, Bf[t * 2],     acc1, 0, 0, 0);
  }

  const int oc = lane & 31, hh = lane >> 5;
  const float bias = b2[oc];
  #pragma unroll
  for (int i2 = 0; i2 < 2; ++i2) {
    const f32x16v& a = i2 ? acc1 : acc0;
    const int py = 2 * wv + i2;
    #pragma unroll
    for (int bq = 0; bq < 2; ++bq)
      #pragma unroll
      for (int rq = 0; rq < 2; ++rq) {
        const int r0 = bq * 4 + rq * 2;
        float v = fmaxf(fmaxf(a[r0], a[r0 + 1]), fmaxf(a[r0 + 8], a[r0 + 9]));
        v = fmaxf(v + bias, 0.f);
        const int px = 2 * hh + 4 * bq + rq;
        const int idx = ((img * 8 + py) * 8 + px) * 32 + oc;
        __bf16 vh = (__bf16)v;
        h2h[idx] = vh;
        h2l[idx] = (__bf16)(v - (float)vh);
      }
  }
}

// ------------------------------------------------------------------- conv3
// MFMA 16x16x32 bf16, split 3-term. 4 images/block, wave=image.
__global__ __launch_bounds__(256) void conv3_kernel(
    const __bf16* __restrict__ h2h, const __bf16* __restrict__ h2l,
    const __bf16* __restrict__ b3p, const float* __restrict__ b3,
    float* __restrict__ h3) {
  __shared__ __align__(16) unsigned short s3[8 * 4000];
  const int tid = threadIdx.x;
  const int b0 = blockIdx.x * 4;

  for (int i = tid; i < 8000; i += 256) ((unsigned long long*)s3)[i] = 0ull;
  __syncthreads();
  for (int e = tid; e < 2048; e += 256) {
    int im = e >> 9, part = (e >> 8) & 1, r = e & 255;
    int ic8 = (r & 3) * 8, xx = (r >> 2) & 7, y = r >> 5;
    const __bf16* src = (part ? h2l : h2h) + ((b0 + im) * 64 + y * 8 + xx) * 32 + ic8;
    uint4 v = *(const uint4*)src;
    *(uint4*)&s3[(im * 2 + part) * 4000 + (y + 1) * 400 + (xx + 1) * 40 + ic8] = v;
  }
  __syncthreads();

  const int lane = tid & 63;
  const int im = tid >> 6;
  const int m = lane & 15, quad = lane >> 4;
  const int xm = m & 7, yoff = m >> 3;
  const int baseh = im * 8000, basel = baseh + 4000;

  f32x4 acc[4][4];
  #pragma unroll
  for (int mt = 0; mt < 4; ++mt)
    #pragma unroll
    for (int nt = 0; nt < 4; ++nt)
      #pragma unroll
      for (int r = 0; r < 4; ++r) acc[mt][nt][r] = 0.f;

  #pragma unroll
  for (int t = 0; t < 9; ++t) {
    const int ky = t / 3, kx = t % 3;
    bf16x8 Bt[8];
    #pragma unroll
    for (int f = 0; f < 8; ++f)
      Bt[f] = *(const bf16x8*)(b3p + (t * 8 + f) * 512 + lane * 8);
    #pragma unroll
    for (int mt = 0; mt < 4; ++mt) {
      const int ro = (2 * mt + yoff + ky) * 400 + (xm + kx) * 40 + quad * 8;
      bf16x8 ah = *(const bf16x8*)&s3[baseh + ro];
      bf16x8 al = *(const bf16x8*)&s3[basel + ro];
      #pragma unroll
      for (int nt = 0; nt < 4; ++nt)
        acc[mt][nt] = __builtin_amdgcn_mfma_f32_16x16x32_bf16(ah, Bt[nt * 2],     acc[mt][nt], 0, 0, 0);
      #pragma unroll
      for (int nt = 0; nt < 4; ++nt)
        acc[mt][nt] = __builtin_amdgcn_mfma_f32_16x16x32_bf16(ah, Bt[nt * 2 + 1], acc[mt][nt], 0, 0, 0);
      #pragma unroll
      for (int nt = 0; nt < 4; ++nt)
        acc[mt][nt] = __builtin_amdgcn_mfma_f32_16x16x32_bf16(al, Bt[nt * 2],     acc[mt][nt], 0, 0, 0);
    }
  }

  const int ocl = lane & 15;
  #pragma unroll
  for (int mt = 0; mt < 4; ++mt)
    #pragma unroll
    for (int nt = 0; nt < 4; ++nt) {
      float p0 = fmaxf(acc[mt][nt][0], acc[mt][nt][1]);
      float p1 = fmaxf(acc[mt][nt][2], acc[mt][nt][3]);
      p0 = fmaxf(p0, __shfl_xor(p0, 32, 64));
      p1 = fmaxf(p1, __shfl_xor(p1, 32, 64));
      if (quad < 2) {
        const int oc = nt * 16 + ocl;
        const float bias = b3[oc];
        const float v0 = fmaxf(p0 + bias, 0.f);
        const float v1 = fmaxf(p1 + bias, 0.f);
        const int base = ((b0 + im) * 64 + oc) * 16 + mt * 4 + (quad & 1) * 2;
        h3[base] = v0;
        h3[base + 1] = v1;
      }
    }
}

// ---------------------------------------------------------------------- fc
__global__ __launch_bounds__(256) void fc_kernel(
    const float* __restrict__ h3, const float* __restrict__ fw,
    const float* __restrict__ fb, float* __restrict__ out) {
  const int tid = threadIdx.x;
  const int lane = tid & 63;
  const int b = blockIdx.x * 4 + (tid >> 6);
  float hv[16];
  #pragma unroll
  for (int i = 0; i < 16; ++i) hv[i] = h3[b * 1024 + i * 64 + lane];
  #pragma unroll
  for (int j = 0; j < 10; ++j) {
    float dot = 0.f;
    #pragma unroll
    for (int i = 0; i < 16; ++i)
      dot = fmaf(hv[i], fw[j * 1024 + i * 64 + lane], dot);
    #pragma unroll
    for (int s = 32; s > 0; s >>= 1) dot += __shfl_xor(dot, s, 64);
    if (lane == 0) out[b * 10 + j] = dot + fb[j];
  }
}

// -------------------------------------------------------------------- launch
extern "C" void kernel_launch(void* const* d_in, const int* in_sizes, int n_in,
                              void* d_out, int out_size, void* d_ws, size_t ws_size,
                              hipStream_t stream) {
  const float* x   = (const float*)d_in[0];
  const float* w1  = (const float*)d_in[1];
  const float* b1  = (const float*)d_in[2];
  const float* w2  = (const float*)d_in[3];
  const float* b2  = (const float*)d_in[4];
  const float* w3  = (const float*)d_in[5];
  const float* b3  = (const float*)d_in[6];
  const float* fcw = (const float*)d_in[7];
  const float* fcb = (const float*)d_in[8];
  float* ws  = (float*)d_ws;
  float* out = (float*)d_out;

  __bf16* h1h = (__bf16*)(ws + H1HI_OFF);
  __bf16* h1l = (__bf16*)(ws + H1LO_OFF);
  __bf16* h2h = (__bf16*)(ws + H2HI_OFF);
  __bf16* h2l = (__bf16*)(ws + H2LO_OFF);
  float*  h3  = ws + H3_OFF;
  __bf16* b2p = (__bf16*)(ws + B2P_OFF);
  __bf16* b3p = (__bf16*)(ws + B3P_OFF);
  __bf16* c1p = (__bf16*)(ws + H3_OFF);   // dead until conv3 overwrites

  hipLaunchKernelGGL(pack_weights, dim3(188), dim3(256), 0, stream,
                     w1, w2, w3, b2p, b3p, c1p);
  hipLaunchKernelGGL(conv1_kernel, dim3(4096), dim3(256), 0, stream, x, c1p, b1, h1h, h1l);
  hipLaunchKernelGGL(conv2_kernel, dim3(4096), dim3(256), 0, stream, h1h, h1l, b2p, b2, h2h, h2l);
  hipLaunchKernelGGL(conv3_kernel, dim3(1024), dim3(256), 0, stream, h2h, h2l, b3p, b3, h3);
  hipLaunchKernelGGL(fc_kernel, dim3(1024), dim3(256), 0, stream, h3, fcw, fcb, out);
}

// Round 6
// 187.910 us; speedup vs baseline: 1.4494x; 1.4494x over previous
//
#include <hip/hip_runtime.h>

typedef float f32x4 __attribute__((ext_vector_type(4)));
typedef float f32x16v __attribute__((ext_vector_type(16)));
typedef __bf16 bf16x4 __attribute__((ext_vector_type(4)));
typedef __bf16 bf16x8 __attribute__((ext_vector_type(8)));

// Workspace layout (float-slot offsets; total 29383168 floats = 117.53 MB):
//   h1_hi bf16[16.78M] @ 0         h1_lo @ 8388608
//   h2_hi bf16[8.39M]  @ 16777216  h2_lo @ 20971520
//   h3    f32 [4.19M]  @ 25165824   (first 1024 floats double as c1p before conv3)
//   b2p   bf16[9216]   @ 29360128  (18 frags x 1024B, 32x32x16 B-layout)
//   b3p   bf16[36864]  @ 29364736  (72 frags x 1024B, 16x16x32 B-layout)
#define H1HI_OFF 0u
#define H1LO_OFF 8388608u
#define H2HI_OFF 16777216u
#define H2LO_OFF 20971520u
#define H3_OFF   25165824u
#define B2P_OFF  29360128u
#define B3P_OFF  29364736u

// ------------------------------------------------------------- pack_weights
// b2p frag f=t*2+p: lane l, j: oc=l&31, ic=(l>>5)*8+j              (32x32x16)
// b3p frag f=t*8+nt*2+p: lane l, j: oc=nt*16+(l&15), ic=(l>>4)*8+j (16x16x32)
// c1p frag f in {B1h,B1l,B2h,B2l}: oc=l&15, k=(l>>4)*8+j,
//   k = kxp*16 + (ky*3+ic); B1: kx=kxp; B2: kx=2 if kxp==0 else zero.
__global__ __launch_bounds__(256) void pack_weights(
    const float* __restrict__ w1, const float* __restrict__ w2,
    const float* __restrict__ w3,
    __bf16* __restrict__ b2p, __bf16* __restrict__ b3p,
    __bf16* __restrict__ c1p) {
  int i = blockIdx.x * 256 + threadIdx.x;
  if (i < 9216) {
    int f = i >> 9, r = i & 511;
    int l = r >> 3, j = r & 7;
    int t = f >> 1, p = f & 1;
    int ky = t / 3, kx = t % 3;
    int oc = l & 31, ic = ((l >> 5) << 3) + j;
    float v = w2[oc * 144 + ic * 9 + ky * 3 + kx];
    __bf16 hi = (__bf16)v;
    b2p[i] = p ? (__bf16)(v - (float)hi) : hi;
  } else if (i < 9216 + 36864) {
    int q = i - 9216;
    int f = q >> 9, r = q & 511;
    int l = r >> 3, j = r & 7;
    int t = f >> 3, nt = (f >> 1) & 3, p = f & 1;
    int ky = t / 3, kx = t % 3;
    int oc = nt * 16 + (l & 15), ic = ((l >> 4) << 3) + j;
    float v = w3[oc * 288 + ic * 9 + ky * 3 + kx];
    __bf16 hi = (__bf16)v;
    b3p[q] = p ? (__bf16)(v - (float)hi) : hi;
  } else if (i < 9216 + 36864 + 2048) {
    int q = i - (9216 + 36864);
    int f = q >> 9, r = q & 511;
    int l = r >> 3, j = r & 7;
    int oc = l & 15, k = ((l >> 4) << 3) + j;
    int kxp = k >> 4, kp = k & 15;
    int grp = f >> 1, p = f & 1;
    float v = 0.f;
    if (kp < 9 && !(grp && kxp)) {
      int ky = kp / 3, ic = kp % 3;
      int kx = grp ? 2 : kxp;
      v = w1[oc * 27 + ic * 9 + ky * 3 + kx];
    }
    __bf16 hi = (__bf16)v;
    c1p[q] = p ? (__bf16)(v - (float)hi) : hi;
  }
}

// ------------------------------------------------------------------- conv1
// MFMA 16x16x32 bf16, 1 image/block, 4 waves (wave w = output rows w*8..w*8+7).
// 3-phase LDS im2col:
//   A: img[row 0..33][col 0..33][ic0..2+pad] bf16  (b64 writes, even banks)
//   B: R[slot=y*34+x'][16]: k'=ky*3+ic at 0..8, zeros 9..15 (2x b128 writes)
//   C: compute — A-frag = one ds_read_b128 (R5-validated mapping).
__global__ __launch_bounds__(256) void conv1_kernel(
    const float* __restrict__ x, const __bf16* __restrict__ c1p,
    const float* __restrict__ b1,
    __bf16* __restrict__ h1h, __bf16* __restrict__ h1l) {
  __shared__ __align__(16) __bf16 s_img[34 * 34 * 4];    // 9248 B
  __shared__ __align__(16) __bf16 R[1088 * 16 + 8];      // 34832 B (+zero slot)
  const int tid = threadIdx.x;
  const int img = blockIdx.x;
  const int w = tid >> 6, lane = tid & 63;

  // zero img halo (whole img) + zero slot
  for (int i = tid; i < 1156; i += 256) ((unsigned long long*)s_img)[i] = 0ull;
  if (tid < 2) ((unsigned long long*)&R[1088 * 16])[tid] = 0ull;
  __syncthreads();

  // Phase A: x[3][32][32] fp32 -> img[(y+1)*34 + x+1][ic], one b64 per pixel
  const float* xg = x + img * 3072;
  for (int i = tid; i < 1024; i += 256) {
    const int y = i >> 5, xx = i & 31;
    bf16x4 pk;
    pk.x = (__bf16)xg[i];
    pk.y = (__bf16)xg[i + 1024];
    pk.z = (__bf16)xg[i + 2048];
    pk.w = (__bf16)0.f;
    *(bf16x4*)&s_img[((y + 1) * 34 + (xx + 1)) * 4] = pk;
  }
  __syncthreads();

  // Phase B: R[s=yq*34+x'][k'=ky*3+ic] = img[(yq+ky)*34+x'][ic]
  for (int s = tid; s < 1088; s += 256) {
    const int yq = s / 34, xp = s - yq * 34;
    const __bf16* ib = &s_img[(yq * 34 + xp) * 4];
    const bf16x4 r0 = *(const bf16x4*)(ib);
    const bf16x4 r1 = *(const bf16x4*)(ib + 136);
    const bf16x4 r2 = *(const bf16x4*)(ib + 272);
    bf16x8 o0;
    o0[0] = r0.x; o0[1] = r0.y; o0[2] = r0.z; o0[3] = r1.x;
    o0[4] = r1.y; o0[5] = r1.z; o0[6] = r2.x; o0[7] = r2.y;
    bf16x8 o1 = {r2.z, (__bf16)0.f, (__bf16)0.f, (__bf16)0.f,
                 (__bf16)0.f, (__bf16)0.f, (__bf16)0.f, (__bf16)0.f};
    *(bf16x8*)&R[s * 16] = o0;
    *(bf16x8*)&R[s * 16 + 8] = o1;
  }

  const bf16x8 B1h = *(const bf16x8*)(c1p + 0 * 512 + lane * 8);
  const bf16x8 B1l = *(const bf16x8*)(c1p + 1 * 512 + lane * 8);
  const bf16x8 B2h = *(const bf16x8*)(c1p + 2 * 512 + lane * 8);
  const bf16x8 B2l = *(const bf16x8*)(c1p + 3 * 512 + lane * 8);
  __syncthreads();

  // Phase C (identical semantics to R5's validated compute)
  const int xm = lane & 15, kg = lane >> 4;
  const bf16x8* Zp = (const bf16x8*)&R[1088 * 16];
  const int oc = lane & 15, quad = lane >> 4;
  const float bias = b1[oc];

  #pragma unroll
  for (int p = 0; p < 4; ++p) {
    f32x4 acc[2][2];
    #pragma unroll
    for (int ys = 0; ys < 2; ++ys)
      #pragma unroll
      for (int xh = 0; xh < 2; ++xh)
        #pragma unroll
        for (int r = 0; r < 4; ++r) acc[ys][xh][r] = 0.f;

    #pragma unroll
    for (int ys = 0; ys < 2; ++ys) {
      const int yqg = w * 8 + p * 2 + ys;
      #pragma unroll
      for (int xh = 0; xh < 2; ++xh) {
        const int xv = xh * 16 + xm;
        const bf16x8 A1 = *(const bf16x8*)&R[((yqg * 34) + xv + (kg >> 1)) * 16 + (kg & 1) * 8];
        const bf16x8 A2 = (kg < 2)
            ? *(const bf16x8*)&R[((yqg * 34) + xv + 2) * 16 + kg * 8]
            : *Zp;
        acc[ys][xh] = __builtin_amdgcn_mfma_f32_16x16x32_bf16(A1, B1h, acc[ys][xh], 0, 0, 0);
        acc[ys][xh] = __builtin_amdgcn_mfma_f32_16x16x32_bf16(A2, B2h, acc[ys][xh], 0, 0, 0);
        acc[ys][xh] = __builtin_amdgcn_mfma_f32_16x16x32_bf16(A1, B1l, acc[ys][xh], 0, 0, 0);
        acc[ys][xh] = __builtin_amdgcn_mfma_f32_16x16x32_bf16(A2, B2l, acc[ys][xh], 0, 0, 0);
      }
    }
    const int py = w * 4 + p;
    #pragma unroll
    for (int xh = 0; xh < 2; ++xh)
      #pragma unroll
      for (int xp2 = 0; xp2 < 2; ++xp2) {
        const float v0 = fmaxf(acc[0][xh][xp2 * 2], acc[0][xh][xp2 * 2 + 1]);
        const float v1 = fmaxf(acc[1][xh][xp2 * 2], acc[1][xh][xp2 * 2 + 1]);
        const float v = fmaxf(fmaxf(v0, v1) + bias, 0.f);
        const int px = xh * 8 + quad * 2 + xp2;
        const int idx = (img * 256 + py * 16 + px) * 16 + oc;
        const __bf16 vh = (__bf16)v;
        h1h[idx] = vh;
        h1l[idx] = (__bf16)(v - (float)vh);
      }
  }
}

// ------------------------------------------------------------------- conv2
// MFMA 32x32x16 bf16, bf16x2 split (3 terms). 1 image/block.
__global__ __launch_bounds__(256) void conv2_kernel(
    const __bf16* __restrict__ h1h, const __bf16* __restrict__ h1l,
    const __bf16* __restrict__ b2p, const float* __restrict__ b2,
    __bf16* __restrict__ h2h, __bf16* __restrict__ h2l) {
  __shared__ __align__(16) unsigned short s2[2 * 7776];
  const int tid = threadIdx.x;
  const int img = blockIdx.x;

  for (int i = tid; i < 3888; i += 256) ((unsigned long long*)s2)[i] = 0ull;
  __syncthreads();
  for (int e = tid; e < 1024; e += 256) {
    int part = e >> 9, r = e & 511;
    int ic8 = (r & 1) * 8, xx = (r >> 1) & 15, y = r >> 5;
    const __bf16* src = (part ? h1l : h1h) + img * 4096 + (y * 16 + xx) * 16 + ic8;
    uint4 v = *(const uint4*)src;
    *(uint4*)&s2[part * 7776 + (y + 1) * 432 + (xx + 1) * 24 + ic8] = v;
  }
  const int lane = tid & 63;
  bf16x8 Bf[18];
  #pragma unroll
  for (int f = 0; f < 18; ++f)
    Bf[f] = *(const bf16x8*)(b2p + f * 512 + lane * 8);
  __syncthreads();

  const int wv = tid >> 6;
  const int xm = lane & 15, yoff = (lane >> 4) & 1, kh = lane >> 5;

  f32x16v acc0, acc1;
  #pragma unroll
  for (int r = 0; r < 16; ++r) { acc0[r] = 0.f; acc1[r] = 0.f; }

  #pragma unroll
  for (int t = 0; t < 9; ++t) {
    const int ky = t / 3, kx = t % 3;
    const int col = (xm + kx) * 24 + kh * 8;
    const int row0 = (4 * wv + yoff + ky) * 432 + col;
    const int row1 = row0 + 864;
    bf16x8 a0h = *(const bf16x8*)&s2[row0];
    bf16x8 a0l = *(const bf16x8*)&s2[7776 + row0];
    bf16x8 a1h = *(const bf16x8*)&s2[row1];
    bf16x8 a1l = *(const bf16x8*)&s2[7776 + row1];
    acc0 = __builtin_amdgcn_mfma_f32_32x32x16_bf16(a0h, Bf[t * 2],     acc0, 0, 0, 0);
    acc1 = __builtin_amdgcn_mfma_f32_32x32x16_bf16(a1h, Bf[t * 2],     acc1, 0, 0, 0);
    acc0 = __builtin_amdgcn_mfma_f32_32x32x16_bf16(a0h, Bf[t * 2 + 1], acc0, 0, 0, 0);
    acc1 = __builtin_amdgcn_mfma_f32_32x32x16_bf16(a1h, Bf[t * 2 + 1], acc1, 0, 0, 0);
    acc0 = __builtin_amdgcn_mfma_f32_32x32x16_bf16(a0l, Bf[t * 2],     acc0, 0, 0, 0);
    acc1 = __builtin_amdgcn_mfma_f32_32x32x16_bf16(a1l, Bf[t * 2],     acc1, 0, 0, 0);
  }

  const int oc = lane & 31, hh = lane >> 5;
  const float bias = b2[oc];
  #pragma unroll
  for (int i2 = 0; i2 < 2; ++i2) {
    const f32x16v& a = i2 ? acc1 : acc0;
    const int py = 2 * wv + i2;
    #pragma unroll
    for (int bq = 0; bq < 2; ++bq)
      #pragma unroll
      for (int rq = 0; rq < 2; ++rq) {
        const int r0 = bq * 4 + rq * 2;
        float v = fmaxf(fmaxf(a[r0], a[r0 + 1]), fmaxf(a[r0 + 8], a[r0 + 9]));
        v = fmaxf(v + bias, 0.f);
        const int px = 2 * hh + 4 * bq + rq;
        const int idx = ((img * 8 + py) * 8 + px) * 32 + oc;
        __bf16 vh = (__bf16)v;
        h2h[idx] = vh;
        h2l[idx] = (__bf16)(v - (float)vh);
      }
  }
}

// ------------------------------------------------------------------- conv3
// MFMA 16x16x32 bf16, split 3-term. 4 images/block, wave=image.
__global__ __launch_bounds__(256) void conv3_kernel(
    const __bf16* __restrict__ h2h, const __bf16* __restrict__ h2l,
    const __bf16* __restrict__ b3p, const float* __restrict__ b3,
    float* __restrict__ h3) {
  __shared__ __align__(16) unsigned short s3[8 * 4000];
  const int tid = threadIdx.x;
  const int b0 = blockIdx.x * 4;

  for (int i = tid; i < 8000; i += 256) ((unsigned long long*)s3)[i] = 0ull;
  __syncthreads();
  for (int e = tid; e < 2048; e += 256) {
    int im = e >> 9, part = (e >> 8) & 1, r = e & 255;
    int ic8 = (r & 3) * 8, xx = (r >> 2) & 7, y = r >> 5;
    const __bf16* src = (part ? h2l : h2h) + ((b0 + im) * 64 + y * 8 + xx) * 32 + ic8;
    uint4 v = *(const uint4*)src;
    *(uint4*)&s3[(im * 2 + part) * 4000 + (y + 1) * 400 + (xx + 1) * 40 + ic8] = v;
  }
  __syncthreads();

  const int lane = tid & 63;
  const int im = tid >> 6;
  const int m = lane & 15, quad = lane >> 4;
  const int xm = m & 7, yoff = m >> 3;
  const int baseh = im * 8000, basel = baseh + 4000;

  f32x4 acc[4][4];
  #pragma unroll
  for (int mt = 0; mt < 4; ++mt)
    #pragma unroll
    for (int nt = 0; nt < 4; ++nt)
      #pragma unroll
      for (int r = 0; r < 4; ++r) acc[mt][nt][r] = 0.f;

  #pragma unroll
  for (int t = 0; t < 9; ++t) {
    const int ky = t / 3, kx = t % 3;
    bf16x8 Bt[8];
    #pragma unroll
    for (int f = 0; f < 8; ++f)
      Bt[f] = *(const bf16x8*)(b3p + (t * 8 + f) * 512 + lane * 8);
    #pragma unroll
    for (int mt = 0; mt < 4; ++mt) {
      const int ro = (2 * mt + yoff + ky) * 400 + (xm + kx) * 40 + quad * 8;
      bf16x8 ah = *(const bf16x8*)&s3[baseh + ro];
      bf16x8 al = *(const bf16x8*)&s3[basel + ro];
      #pragma unroll
      for (int nt = 0; nt < 4; ++nt)
        acc[mt][nt] = __builtin_amdgcn_mfma_f32_16x16x32_bf16(ah, Bt[nt * 2],     acc[mt][nt], 0, 0, 0);
      #pragma unroll
      for (int nt = 0; nt < 4; ++nt)
        acc[mt][nt] = __builtin_amdgcn_mfma_f32_16x16x32_bf16(ah, Bt[nt * 2 + 1], acc[mt][nt], 0, 0, 0);
      #pragma unroll
      for (int nt = 0; nt < 4; ++nt)
        acc[mt][nt] = __builtin_amdgcn_mfma_f32_16x16x32_bf16(al, Bt[nt * 2],     acc[mt][nt], 0, 0, 0);
    }
  }

  const int ocl = lane & 15;
  #pragma unroll
  for (int mt = 0; mt < 4; ++mt)
    #pragma unroll
    for (int nt = 0; nt < 4; ++nt) {
      float p0 = fmaxf(acc[mt][nt][0], acc[mt][nt][1]);
      float p1 = fmaxf(acc[mt][nt][2], acc[mt][nt][3]);
      p0 = fmaxf(p0, __shfl_xor(p0, 32, 64));
      p1 = fmaxf(p1, __shfl_xor(p1, 32, 64));
      if (quad < 2) {
        const int oc = nt * 16 + ocl;
        const float bias = b3[oc];
        const float v0 = fmaxf(p0 + bias, 0.f);
        const float v1 = fmaxf(p1 + bias, 0.f);
        const int base = ((b0 + im) * 64 + oc) * 16 + mt * 4 + (quad & 1) * 2;
        h3[base] = v0;
        h3[base + 1] = v1;
      }
    }
}

// ---------------------------------------------------------------------- fc
__global__ __launch_bounds__(256) void fc_kernel(
    const float* __restrict__ h3, const float* __restrict__ fw,
    const float* __restrict__ fb, float* __restrict__ out) {
  const int tid = threadIdx.x;
  const int lane = tid & 63;
  const int b = blockIdx.x * 4 + (tid >> 6);
  float hv[16];
  #pragma unroll
  for (int i = 0; i < 16; ++i) hv[i] = h3[b * 1024 + i * 64 + lane];
  #pragma unroll
  for (int j = 0; j < 10; ++j) {
    float dot = 0.f;
    #pragma unroll
    for (int i = 0; i < 16; ++i)
      dot = fmaf(hv[i], fw[j * 1024 + i * 64 + lane], dot);
    #pragma unroll
    for (int s = 32; s > 0; s >>= 1) dot += __shfl_xor(dot, s, 64);
    if (lane == 0) out[b * 10 + j] = dot + fb[j];
  }
}

// -------------------------------------------------------------------- launch
extern "C" void kernel_launch(void* const* d_in, const int* in_sizes, int n_in,
                              void* d_out, int out_size, void* d_ws, size_t ws_size,
                              hipStream_t stream) {
  const float* x   = (const float*)d_in[0];
  const float* w1  = (const float*)d_in[1];
  const float* b1  = (const float*)d_in[2];
  const float* w2  = (const float*)d_in[3];
  const float* b2  = (const float*)d_in[4];
  const float* w3  = (const float*)d_in[5];
  const float* b3  = (const float*)d_in[6];
  const float* fcw = (const float*)d_in[7];
  const float* fcb = (const float*)d_in[8];
  float* ws  = (float*)d_ws;
  float* out = (float*)d_out;

  __bf16* h1h = (__bf16*)(ws + H1HI_OFF);
  __bf16* h1l = (__bf16*)(ws + H1LO_OFF);
  __bf16* h2h = (__bf16*)(ws + H2HI_OFF);
  __bf16* h2l = (__bf16*)(ws + H2LO_OFF);
  float*  h3  = ws + H3_OFF;
  __bf16* b2p = (__bf16*)(ws + B2P_OFF);
  __bf16* b3p = (__bf16*)(ws + B3P_OFF);
  __bf16* c1p = (__bf16*)(ws + H3_OFF);   // dead until conv3 overwrites

  hipLaunchKernelGGL(pack_weights, dim3(188), dim3(256), 0, stream,
                     w1, w2, w3, b2p, b3p, c1p);
  hipLaunchKernelGGL(conv1_kernel, dim3(4096), dim3(256), 0, stream, x, c1p, b1, h1h, h1l);
  hipLaunchKernelGGL(conv2_kernel, dim3(4096), dim3(256), 0, stream, h1h, h1l, b2p, b2, h2h, h2l);
  hipLaunchKernelGGL(conv3_kernel, dim3(1024), dim3(256), 0, stream, h2h, h2l, b3p, b3, h3);
  hipLaunchKernelGGL(fc_kernel, dim3(1024), dim3(256), 0, stream, h3, fcw, fcb, out);
}

// Round 7
// 179.620 us; speedup vs baseline: 1.5163x; 1.0462x over previous
//
#include <hip/hip_runtime.h>

typedef float f32x4 __attribute__((ext_vector_type(4)));
typedef float f32x16v __attribute__((ext_vector_type(16)));
typedef __bf16 bf16x4 __attribute__((ext_vector_type(4)));
typedef __bf16 bf16x8 __attribute__((ext_vector_type(8)));

// ws layout (bf16 elements): b2p[9216] @0, b3p[36864] @9216, c1p[2048] @46080
#define B2P_OFF 0
#define B3P_OFF 9216
#define C1P_OFF 46080

// ------------------------------------------------------------- pack_weights
// b2p frag f=t*2+p: lane l, j: oc=l&31, ic=(l>>5)*8+j              (32x32x16)
// b3p frag f=t*8+nt*2+p: lane l, j: oc=nt*16+(l&15), ic=(l>>4)*8+j (16x16x32)
// c1p frag f in {B1h,B1l,B2h,B2l}: oc=l&15, k=(l>>4)*8+j,
//   k = kxp*16 + (ky*3+ic); B1: kx=kxp; B2: kx=2 if kxp==0 else zero.
__global__ __launch_bounds__(256) void pack_weights(
    const float* __restrict__ w1, const float* __restrict__ w2,
    const float* __restrict__ w3, __bf16* __restrict__ wsb) {
  int i = blockIdx.x * 256 + threadIdx.x;
  if (i < 9216) {
    int f = i >> 9, r = i & 511;
    int l = r >> 3, j = r & 7;
    int t = f >> 1, p = f & 1;
    int ky = t / 3, kx = t % 3;
    int oc = l & 31, ic = ((l >> 5) << 3) + j;
    float v = w2[oc * 144 + ic * 9 + ky * 3 + kx];
    __bf16 hi = (__bf16)v;
    wsb[B2P_OFF + i] = p ? (__bf16)(v - (float)hi) : hi;
  } else if (i < 9216 + 36864) {
    int q = i - 9216;
    int f = q >> 9, r = q & 511;
    int l = r >> 3, j = r & 7;
    int t = f >> 3, nt = (f >> 1) & 3, p = f & 1;
    int ky = t / 3, kx = t % 3;
    int oc = nt * 16 + (l & 15), ic = ((l >> 4) << 3) + j;
    float v = w3[oc * 288 + ic * 9 + ky * 3 + kx];
    __bf16 hi = (__bf16)v;
    wsb[B3P_OFF + q] = p ? (__bf16)(v - (float)hi) : hi;
  } else if (i < 9216 + 36864 + 2048) {
    int q = i - (9216 + 36864);
    int f = q >> 9, r = q & 511;
    int l = r >> 3, j = r & 7;
    int oc = l & 15, k = ((l >> 4) << 3) + j;
    int kxp = k >> 4, kp = k & 15;
    int grp = f >> 1, p = f & 1;
    float v = 0.f;
    if (kp < 9 && !(grp && kxp)) {
      int ky = kp / 3, ic = kp % 3;
      int kx = grp ? 2 : kxp;
      v = w1[oc * 27 + ic * 9 + ky * 3 + kx];
    }
    __bf16 hi = (__bf16)v;
    wsb[C1P_OFF + q] = p ? (__bf16)(v - (float)hi) : hi;
  }
}

// -------------------------------------------------------------- fused CNN
// 1 image per block, 4 waves. LDS union (47168 B, 3 blocks/CU):
//   phase1: s_img @0 (9248B) | R @9248 (34816B + 16B zero slot)
//   phase2: s2 @0 (31104B = 2 parts x 18x18 cells x 24 slots)
//   phase3: s3 @31104 (16000B = 2 parts x 10x10 cells x 40 slots)
//   phase4: h3s @0 (4096B, f32 [oc][py][px])
__global__ __launch_bounds__(256, 3) void cnn_fused(
    const float* __restrict__ x, const __bf16* __restrict__ wsb,
    const float* __restrict__ b1, const float* __restrict__ b2,
    const float* __restrict__ b3,
    const float* __restrict__ fcw, const float* __restrict__ fcb,
    float* __restrict__ out) {
  __shared__ __align__(16) unsigned char smem[47168];
  __bf16* s_img = (__bf16*)smem;                        // 34*34*4 bf16
  __bf16* R     = (__bf16*)(smem + 9248);               // 1088*16 + 8 zero
  __bf16* s2b   = (__bf16*)smem;                        // 2*7776
  __bf16* s3b   = (__bf16*)(smem + 31104);              // 2*4000
  float*  h3s   = (float*)smem;                         // 1024 f32

  const __bf16* b2p = wsb + B2P_OFF;
  const __bf16* b3p = wsb + B3P_OFF;
  const __bf16* c1p = wsb + C1P_OFF;

  const int tid = threadIdx.x;
  const int img = blockIdx.x;
  const int w = tid >> 6, lane = tid & 63;

  // ---------------- phase 1: zero s_img + R zero-slot
  for (int i = tid; i < 1156; i += 256) ((unsigned long long*)s_img)[i] = 0ull;
  if (tid < 2) ((unsigned long long*)&R[1088 * 16])[tid] = 0ull;
  __syncthreads();

  // phase A: x[3][32][32] fp32 -> s_img[(y+1)*34 + x+1][ic0..2], b64/px
  const float* xg = x + img * 3072;
  for (int i = tid; i < 1024; i += 256) {
    const int y = i >> 5, xx = i & 31;
    bf16x4 pk;
    pk.x = (__bf16)xg[i];
    pk.y = (__bf16)xg[i + 1024];
    pk.z = (__bf16)xg[i + 2048];
    pk.w = (__bf16)0.f;
    *(bf16x4*)&s_img[((y + 1) * 34 + (xx + 1)) * 4] = pk;
  }
  __syncthreads();

  // phase B: R[s=yq*34+x'][k'=ky*3+ic] = s_img[(yq+ky)*34+x'][ic]
  for (int s = tid; s < 1088; s += 256) {
    const int yq = s / 34, xp = s - yq * 34;
    const __bf16* ib = &s_img[(yq * 34 + xp) * 4];
    const bf16x4 r0 = *(const bf16x4*)(ib);
    const bf16x4 r1 = *(const bf16x4*)(ib + 136);
    const bf16x4 r2 = *(const bf16x4*)(ib + 272);
    bf16x8 o0;
    o0[0] = r0.x; o0[1] = r0.y; o0[2] = r0.z; o0[3] = r1.x;
    o0[4] = r1.y; o0[5] = r1.z; o0[6] = r2.x; o0[7] = r2.y;
    bf16x8 o1 = {r2.z, (__bf16)0.f, (__bf16)0.f, (__bf16)0.f,
                 (__bf16)0.f, (__bf16)0.f, (__bf16)0.f, (__bf16)0.f};
    *(bf16x8*)&R[s * 16] = o0;
    *(bf16x8*)&R[s * 16 + 8] = o1;
  }
  const bf16x8 B1h = *(const bf16x8*)(c1p + 0 * 512 + lane * 8);
  const bf16x8 B1l = *(const bf16x8*)(c1p + 1 * 512 + lane * 8);
  const bf16x8 B2h = *(const bf16x8*)(c1p + 2 * 512 + lane * 8);
  const bf16x8 B2l = *(const bf16x8*)(c1p + 3 * 512 + lane * 8);
  __syncthreads();

  // ---------------- conv1 compute (R6-validated), pooled results -> regs
  float pooled[16];
  {
    const int xm = lane & 15, kg = lane >> 4;
    const bf16x8* Zp = (const bf16x8*)&R[1088 * 16];
    #pragma unroll
    for (int p = 0; p < 4; ++p) {
      f32x4 acc[2][2];
      #pragma unroll
      for (int ys = 0; ys < 2; ++ys)
        #pragma unroll
        for (int xh = 0; xh < 2; ++xh)
          #pragma unroll
          for (int r = 0; r < 4; ++r) acc[ys][xh][r] = 0.f;
      #pragma unroll
      for (int ys = 0; ys < 2; ++ys) {
        const int yqg = w * 8 + p * 2 + ys;
        #pragma unroll
        for (int xh = 0; xh < 2; ++xh) {
          const int xv = xh * 16 + xm;
          const bf16x8 A1 = *(const bf16x8*)&R[((yqg * 34) + xv + (kg >> 1)) * 16 + (kg & 1) * 8];
          const bf16x8 A2 = (kg < 2)
              ? *(const bf16x8*)&R[((yqg * 34) + xv + 2) * 16 + kg * 8]
              : *Zp;
          acc[ys][xh] = __builtin_amdgcn_mfma_f32_16x16x32_bf16(A1, B1h, acc[ys][xh], 0, 0, 0);
          acc[ys][xh] = __builtin_amdgcn_mfma_f32_16x16x32_bf16(A2, B2h, acc[ys][xh], 0, 0, 0);
          acc[ys][xh] = __builtin_amdgcn_mfma_f32_16x16x32_bf16(A1, B1l, acc[ys][xh], 0, 0, 0);
          acc[ys][xh] = __builtin_amdgcn_mfma_f32_16x16x32_bf16(A2, B2l, acc[ys][xh], 0, 0, 0);
        }
      }
      #pragma unroll
      for (int xh = 0; xh < 2; ++xh)
        #pragma unroll
        for (int xp2 = 0; xp2 < 2; ++xp2) {
          const float v0 = fmaxf(acc[0][xh][xp2 * 2], acc[0][xh][xp2 * 2 + 1]);
          const float v1 = fmaxf(acc[1][xh][xp2 * 2], acc[1][xh][xp2 * 2 + 1]);
          pooled[p * 4 + xh * 2 + xp2] = fmaxf(v0, v1);
        }
    }
  }
  __syncthreads();   // all waves done reading R; s_img/R regions now dead

  // ---------------- write h1 (bias+relu+split) into s2 layout; zero halo
  for (int i = tid; i < 136; i += 256) {
    int part = i >= 68, c = part ? i - 68 : i;
    int row, col;
    if (c < 18)      { row = 0;      col = c; }
    else if (c < 36) { row = 17;     col = c - 18; }
    else if (c < 52) { row = c - 35; col = 0; }
    else             { row = c - 51; col = 17; }
    unsigned long long* p = (unsigned long long*)&s2b[part * 7776 + row * 432 + col * 24];
    p[0] = 0ull; p[1] = 0ull; p[2] = 0ull; p[3] = 0ull;
  }
  {
    const int oc = lane & 15, quad = lane >> 4;
    const float bias = b1[oc];
    #pragma unroll
    for (int p = 0; p < 4; ++p)
      #pragma unroll
      for (int xh = 0; xh < 2; ++xh)
        #pragma unroll
        for (int xp2 = 0; xp2 < 2; ++xp2) {
          const float v = fmaxf(pooled[p * 4 + xh * 2 + xp2] + bias, 0.f);
          const int py = w * 4 + p, px = xh * 8 + quad * 2 + xp2;
          const int a = (py + 1) * 432 + (px + 1) * 24 + oc;
          const __bf16 vh = (__bf16)v;
          s2b[a] = vh;
          s2b[7776 + a] = (__bf16)(v - (float)vh);
        }
  }
  // conv2 B fragments (L2-hot after first blocks)
  bf16x8 Bf[18];
  #pragma unroll
  for (int f = 0; f < 18; ++f)
    Bf[f] = *(const bf16x8*)(b2p + f * 512 + lane * 8);
  __syncthreads();

  // ---------------- conv2 compute (R4-validated), pooled -> s3
  float pooled2[8];
  {
    const unsigned short* s2 = (const unsigned short*)s2b;
    const int xm = lane & 15, yoff = (lane >> 4) & 1, kh = lane >> 5;
    f32x16v acc0, acc1;
    #pragma unroll
    for (int r = 0; r < 16; ++r) { acc0[r] = 0.f; acc1[r] = 0.f; }
    #pragma unroll
    for (int t = 0; t < 9; ++t) {
      const int ky = t / 3, kx = t % 3;
      const int col = (xm + kx) * 24 + kh * 8;
      const int row0 = (4 * w + yoff + ky) * 432 + col;
      const int row1 = row0 + 864;
      bf16x8 a0h = *(const bf16x8*)&s2[row0];
      bf16x8 a0l = *(const bf16x8*)&s2[7776 + row0];
      bf16x8 a1h = *(const bf16x8*)&s2[row1];
      bf16x8 a1l = *(const bf16x8*)&s2[7776 + row1];
      acc0 = __builtin_amdgcn_mfma_f32_32x32x16_bf16(a0h, Bf[t * 2],     acc0, 0, 0, 0);
      acc1 = __builtin_amdgcn_mfma_f32_32x32x16_bf16(a1h, Bf[t * 2],     acc1, 0, 0, 0);
      acc0 = __builtin_amdgcn_mfma_f32_32x32x16_bf16(a0h, Bf[t * 2 + 1], acc0, 0, 0, 0);
      acc1 = __builtin_amdgcn_mfma_f32_32x32x16_bf16(a1h, Bf[t * 2 + 1], acc1, 0, 0, 0);
      acc0 = __builtin_amdgcn_mfma_f32_32x32x16_bf16(a0l, Bf[t * 2],     acc0, 0, 0, 0);
      acc1 = __builtin_amdgcn_mfma_f32_32x32x16_bf16(a1l, Bf[t * 2],     acc1, 0, 0, 0);
    }
    #pragma unroll
    for (int i2 = 0; i2 < 2; ++i2) {
      const f32x16v& a = i2 ? acc1 : acc0;
      #pragma unroll
      for (int bq = 0; bq < 2; ++bq)
        #pragma unroll
        for (int rq = 0; rq < 2; ++rq) {
          const int r0 = bq * 4 + rq * 2;
          pooled2[i2 * 4 + bq * 2 + rq] =
              fmaxf(fmaxf(a[r0], a[r0 + 1]), fmaxf(a[r0 + 8], a[r0 + 9]));
        }
    }
  }
  // s3 halo zero + value writes (s3 disjoint from s2; no sync needed yet)
  for (int i = tid; i < 72; i += 256) {
    int part = i >= 36, c = part ? i - 36 : i;
    int row, col;
    if (c < 10)      { row = 0;      col = c; }
    else if (c < 20) { row = 9;      col = c - 10; }
    else if (c < 28) { row = c - 19; col = 0; }
    else             { row = c - 27; col = 9; }
    unsigned long long* p = (unsigned long long*)&s3b[part * 4000 + row * 400 + col * 40];
    #pragma unroll
    for (int u = 0; u < 8; ++u) p[u] = 0ull;
  }
  {
    const int oc = lane & 31, hh = lane >> 5;
    const float bias = b2[oc];
    #pragma unroll
    for (int i2 = 0; i2 < 2; ++i2)
      #pragma unroll
      for (int bq = 0; bq < 2; ++bq)
        #pragma unroll
        for (int rq = 0; rq < 2; ++rq) {
          const float v = fmaxf(pooled2[i2 * 4 + bq * 2 + rq] + bias, 0.f);
          const int py = 2 * w + i2, px = 2 * hh + 4 * bq + rq;
          const int a = (py + 1) * 400 + (px + 1) * 40 + oc;
          const __bf16 vh = (__bf16)v;
          s3b[a] = vh;
          s3b[4000 + a] = (__bf16)(v - (float)vh);
        }
  }
  __syncthreads();   // s2 dead; s3 complete

  // ---------------- conv3 (wave = nt = oc-tile), R4-validated math
  {
    const unsigned short* s3 = (const unsigned short*)s3b;
    const int nt = w;
    bf16x8 Bt[18];
    #pragma unroll
    for (int t = 0; t < 9; ++t) {
      Bt[t * 2]     = *(const bf16x8*)(b3p + (t * 8 + nt * 2) * 512 + lane * 8);
      Bt[t * 2 + 1] = *(const bf16x8*)(b3p + (t * 8 + nt * 2 + 1) * 512 + lane * 8);
    }
    const int m = lane & 15, quad = lane >> 4;
    const int xm = m & 7, yoff = m >> 3;
    f32x4 acc[4];
    #pragma unroll
    for (int mt = 0; mt < 4; ++mt)
      #pragma unroll
      for (int r = 0; r < 4; ++r) acc[mt][r] = 0.f;
    #pragma unroll
    for (int t = 0; t < 9; ++t) {
      const int ky = t / 3, kx = t % 3;
      #pragma unroll
      for (int mt = 0; mt < 4; ++mt) {
        const int ro = (2 * mt + yoff + ky) * 400 + (xm + kx) * 40 + quad * 8;
        bf16x8 ah = *(const bf16x8*)&s3[ro];
        bf16x8 al = *(const bf16x8*)&s3[4000 + ro];
        acc[mt] = __builtin_amdgcn_mfma_f32_16x16x32_bf16(ah, Bt[t * 2],     acc[mt], 0, 0, 0);
        acc[mt] = __builtin_amdgcn_mfma_f32_16x16x32_bf16(ah, Bt[t * 2 + 1], acc[mt], 0, 0, 0);
        acc[mt] = __builtin_amdgcn_mfma_f32_16x16x32_bf16(al, Bt[t * 2],     acc[mt], 0, 0, 0);
      }
    }
    // epilogue -> h3s[oc*16 + py*4 + px] (h3s overlaps dead s2 only)
    const int ocl = lane & 15;
    #pragma unroll
    for (int mt = 0; mt < 4; ++mt) {
      float p0 = fmaxf(acc[mt][0], acc[mt][1]);
      float p1 = fmaxf(acc[mt][2], acc[mt][3]);
      p0 = fmaxf(p0, __shfl_xor(p0, 32, 64));
      p1 = fmaxf(p1, __shfl_xor(p1, 32, 64));
      if (quad < 2) {
        const int oc = nt * 16 + ocl;
        const float bias = b3[oc];
        const int base = oc * 16 + mt * 4 + (quad & 1) * 2;
        h3s[base]     = fmaxf(p0 + bias, 0.f);
        h3s[base + 1] = fmaxf(p1 + bias, 0.f);
      }
    }
  }
  __syncthreads();

  // ---------------- fc (wave 0)
  if (w == 0) {
    float hv[16];
    #pragma unroll
    for (int i = 0; i < 16; ++i) hv[i] = h3s[i * 64 + lane];
    #pragma unroll
    for (int j = 0; j < 10; ++j) {
      float dot = 0.f;
      #pragma unroll
      for (int i = 0; i < 16; ++i)
        dot = fmaf(hv[i], fcw[j * 1024 + i * 64 + lane], dot);
      #pragma unroll
      for (int s = 32; s > 0; s >>= 1) dot += __shfl_xor(dot, s, 64);
      if (lane == 0) out[img * 10 + j] = dot + fcb[j];
    }
  }
}

// -------------------------------------------------------------------- launch
extern "C" void kernel_launch(void* const* d_in, const int* in_sizes, int n_in,
                              void* d_out, int out_size, void* d_ws, size_t ws_size,
                              hipStream_t stream) {
  const float* x   = (const float*)d_in[0];
  const float* w1  = (const float*)d_in[1];
  const float* b1  = (const float*)d_in[2];
  const float* w2  = (const float*)d_in[3];
  const float* b2  = (const float*)d_in[4];
  const float* w3  = (const float*)d_in[5];
  const float* b3  = (const float*)d_in[6];
  const float* fcw = (const float*)d_in[7];
  const float* fcb = (const float*)d_in[8];
  __bf16* wsb = (__bf16*)d_ws;
  float* out = (float*)d_out;

  hipLaunchKernelGGL(pack_weights, dim3(188), dim3(256), 0, stream, w1, w2, w3, wsb);
  hipLaunchKernelGGL(cnn_fused, dim3(4096), dim3(256), 0, stream,
                     x, wsb, b1, b2, b3, fcw, fcb, out);
}

// Round 8
// 163.622 us; speedup vs baseline: 1.6645x; 1.0978x over previous
//
#include <hip/hip_runtime.h>

typedef float f32x4 __attribute__((ext_vector_type(4)));
typedef float f32x16v __attribute__((ext_vector_type(16)));
typedef __bf16 bf16x4 __attribute__((ext_vector_type(4)));
typedef __bf16 bf16x8 __attribute__((ext_vector_type(8)));

union U4B8 { uint4 u; bf16x8 b; };

// ws layout (bf16 elements): b2p[9216] @0, b3p[36864] @9216, c1p[2048] @46080
#define B2P_OFF 0
#define B3P_OFF 9216
#define C1P_OFF 46080

// ------------------------------------------------------------- pack_weights
// b2p frag f=t*2+p: lane l, j: oc=l&31, ic=(l>>5)*8+j              (32x32x16)
// b3p frag f=t*8+nt*2+p: lane l, j: oc=nt*16+(l&15), ic=(l>>4)*8+j (16x16x32)
// c1p frag f in {B1h,B1l,B2h,B2l}: oc=l&15, k=(l>>4)*8+j,
//   k = kxp*16 + (ky*3+ic); B1: kx=kxp; B2: kx=2 if kxp==0 else zero.
__global__ __launch_bounds__(256) void pack_weights(
    const float* __restrict__ w1, const float* __restrict__ w2,
    const float* __restrict__ w3, __bf16* __restrict__ wsb) {
  int i = blockIdx.x * 256 + threadIdx.x;
  if (i < 9216) {
    int f = i >> 9, r = i & 511;
    int l = r >> 3, j = r & 7;
    int t = f >> 1, p = f & 1;
    int ky = t / 3, kx = t % 3;
    int oc = l & 31, ic = ((l >> 5) << 3) + j;
    float v = w2[oc * 144 + ic * 9 + ky * 3 + kx];
    __bf16 hi = (__bf16)v;
    wsb[B2P_OFF + i] = p ? (__bf16)(v - (float)hi) : hi;
  } else if (i < 9216 + 36864) {
    int q = i - 9216;
    int f = q >> 9, r = q & 511;
    int l = r >> 3, j = r & 7;
    int t = f >> 3, nt = (f >> 1) & 3, p = f & 1;
    int ky = t / 3, kx = t % 3;
    int oc = nt * 16 + (l & 15), ic = ((l >> 4) << 3) + j;
    float v = w3[oc * 288 + ic * 9 + ky * 3 + kx];
    __bf16 hi = (__bf16)v;
    wsb[B3P_OFF + q] = p ? (__bf16)(v - (float)hi) : hi;
  } else if (i < 9216 + 36864 + 2048) {
    int q = i - (9216 + 36864);
    int f = q >> 9, r = q & 511;
    int l = r >> 3, j = r & 7;
    int oc = l & 15, k = ((l >> 4) << 3) + j;
    int kxp = k >> 4, kp = k & 15;
    int grp = f >> 1, p = f & 1;
    float v = 0.f;
    if (kp < 9 && !(grp && kxp)) {
      int ky = kp / 3, ic = kp % 3;
      int kx = grp ? 2 : kxp;
      v = w1[oc * 27 + ic * 9 + ky * 3 + kx];
    }
    __bf16 hi = (__bf16)v;
    wsb[C1P_OFF + q] = p ? (__bf16)(v - (float)hi) : hi;
  }
}

// -------------------------------------------------------------- fused CNN
// 1 image/block, 4 waves. LDS union (32256 B -> 4 blocks/CU with VGPR<=128):
//   phase1: s_img @0 (9248B; cell = 4 ush [ic0,ic1,ic2,0])
//   phase2: s2 @0 (2 parts x 18 rows x 448 ush = 32256B; cell 24 ush)
//   phase3: s3 @0 (2 parts x 10 rows x 448 ush = 17920B; cell 40 ush)
//           h3s @17920 (4096B f32 [oc][py][px])
__global__ __launch_bounds__(256, 4) void cnn_fused(
    const float* __restrict__ x, const __bf16* __restrict__ wsb,
    const float* __restrict__ b1, const float* __restrict__ b2,
    const float* __restrict__ b3,
    const float* __restrict__ fcw, const float* __restrict__ fcb,
    float* __restrict__ out) {
  __shared__ __align__(16) unsigned char smem[32256];
  __bf16* s_img = (__bf16*)smem;
  __bf16* s2b   = (__bf16*)smem;
  __bf16* s3b   = (__bf16*)smem;
  float*  h3s   = (float*)(smem + 17920);

  const __bf16* b2p = wsb + B2P_OFF;
  const __bf16* b3p = wsb + B3P_OFF;
  const __bf16* c1p = wsb + C1P_OFF;

  const int tid = threadIdx.x;
  const int img = blockIdx.x;
  const int w = tid >> 6, lane = tid & 63;

  // ---- phase 1: zero s_img halo (132 cells) + write interior (disjoint)
  if (tid < 132) {
    int row, col;
    if (tid < 34)       { row = 0;        col = tid; }
    else if (tid < 68)  { row = 33;       col = tid - 34; }
    else if (tid < 100) { row = tid - 67; col = 0; }
    else                { row = tid - 99; col = 33; }
    *(unsigned long long*)&s_img[(row * 34 + col) * 4] = 0ull;
  }
  const float* xg = x + img * 3072;
  for (int i = tid; i < 1024; i += 256) {
    const int y = i >> 5, xx = i & 31;
    bf16x4 pk;
    pk.x = (__bf16)xg[i];
    pk.y = (__bf16)xg[i + 1024];
    pk.z = (__bf16)xg[i + 2048];
    pk.w = (__bf16)0.f;
    *(bf16x4*)&s_img[((y + 1) * 34 + (xx + 1)) * 4] = pk;
  }
  const bf16x8 B1h = *(const bf16x8*)(c1p + 0 * 512 + lane * 8);
  const bf16x8 B1l = *(const bf16x8*)(c1p + 1 * 512 + lane * 8);
  const bf16x8 B2h = *(const bf16x8*)(c1p + 2 * 512 + lane * 8);
  const bf16x8 B2l = *(const bf16x8*)(c1p + 3 * 512 + lane * 8);
  __syncthreads();

  // ---- conv1: in-loop A-frag build from s_img (R6-validated k-mapping)
  float pooled[16];
  {
    const int xm = lane & 15, kg = lane >> 4;
    #pragma unroll
    for (int p = 0; p < 4; ++p) {
      f32x4 acc[2][2];
      #pragma unroll
      for (int ys = 0; ys < 2; ++ys)
        #pragma unroll
        for (int xh = 0; xh < 2; ++xh)
          #pragma unroll
          for (int r = 0; r < 4; ++r) acc[ys][xh][r] = 0.f;
      #pragma unroll
      for (int ys = 0; ys < 2; ++ys) {
        const int yqg = w * 8 + p * 2 + ys;
        #pragma unroll
        for (int xh = 0; xh < 2; ++xh) {
          const int xv = xh * 16 + xm;
          // A1: col c1 = xv + (kg>>1); k-half = kg&1
          const int c1 = xv + (kg >> 1);
          const uint2 q0 = *(const uint2*)&s_img[((yqg + 0) * 34 + c1) * 4];
          const uint2 q1 = *(const uint2*)&s_img[((yqg + 1) * 34 + c1) * 4];
          const uint2 q2 = *(const uint2*)&s_img[((yqg + 2) * 34 + c1) * 4];
          U4B8 a1;
          {
            const uint lo0 = q0.x;
            const uint lo1 = q0.y | (q1.x << 16);
            const uint lo2 = (q1.x >> 16) | (q1.y << 16);
            const uint lo3 = q2.x;
            const uint hi0 = q2.y;
            a1.u.x = (kg & 1) ? hi0 : lo0;
            a1.u.y = (kg & 1) ? 0u : lo1;
            a1.u.z = (kg & 1) ? 0u : lo2;
            a1.u.w = (kg & 1) ? 0u : lo3;
          }
          // A2: col xv+2; kg==0 -> lo, kg==1 -> hi, kg>=2 -> zero
          const int c2 = xv + 2;
          const uint2 p0 = *(const uint2*)&s_img[((yqg + 0) * 34 + c2) * 4];
          const uint2 p1 = *(const uint2*)&s_img[((yqg + 1) * 34 + c2) * 4];
          const uint2 p2 = *(const uint2*)&s_img[((yqg + 2) * 34 + c2) * 4];
          U4B8 a2;
          {
            const uint lo0 = p0.x;
            const uint lo1 = p0.y | (p1.x << 16);
            const uint lo2 = (p1.x >> 16) | (p1.y << 16);
            const uint lo3 = p2.x;
            const uint hi0 = p2.y;
            a2.u.x = (kg == 0) ? lo0 : ((kg == 1) ? hi0 : 0u);
            a2.u.y = (kg == 0) ? lo1 : 0u;
            a2.u.z = (kg == 0) ? lo2 : 0u;
            a2.u.w = (kg == 0) ? lo3 : 0u;
          }
          acc[ys][xh] = __builtin_amdgcn_mfma_f32_16x16x32_bf16(a1.b, B1h, acc[ys][xh], 0, 0, 0);
          acc[ys][xh] = __builtin_amdgcn_mfma_f32_16x16x32_bf16(a2.b, B2h, acc[ys][xh], 0, 0, 0);
          acc[ys][xh] = __builtin_amdgcn_mfma_f32_16x16x32_bf16(a1.b, B1l, acc[ys][xh], 0, 0, 0);
          acc[ys][xh] = __builtin_amdgcn_mfma_f32_16x16x32_bf16(a2.b, B2l, acc[ys][xh], 0, 0, 0);
        }
      }
      #pragma unroll
      for (int xh = 0; xh < 2; ++xh)
        #pragma unroll
        for (int xp2 = 0; xp2 < 2; ++xp2) {
          const float v0 = fmaxf(acc[0][xh][xp2 * 2], acc[0][xh][xp2 * 2 + 1]);
          const float v1 = fmaxf(acc[1][xh][xp2 * 2], acc[1][xh][xp2 * 2 + 1]);
          pooled[p * 4 + xh * 2 + xp2] = fmaxf(v0, v1);
        }
    }
  }
  __syncthreads();   // s_img dead

  // ---- h1 (bias+relu+split) -> s2 (row stride 448, part stride 8064)
  for (int i = tid; i < 136; i += 256) {
    int part = i >= 68, c = part ? i - 68 : i;
    int row, col;
    if (c < 18)      { row = 0;      col = c; }
    else if (c < 36) { row = 17;     col = c - 18; }
    else if (c < 52) { row = c - 35; col = 0; }
    else             { row = c - 51; col = 17; }
    unsigned long long* p = (unsigned long long*)&s2b[part * 8064 + row * 448 + col * 24];
    p[0] = 0ull; p[1] = 0ull; p[2] = 0ull; p[3] = 0ull;
  }
  {
    const int oc = lane & 15, quad = lane >> 4;
    const float bias = b1[oc];
    #pragma unroll
    for (int p = 0; p < 4; ++p)
      #pragma unroll
      for (int xh = 0; xh < 2; ++xh)
        #pragma unroll
        for (int xp2 = 0; xp2 < 2; ++xp2) {
          const float v = fmaxf(pooled[p * 4 + xh * 2 + xp2] + bias, 0.f);
          const int py = w * 4 + p, px = xh * 8 + quad * 2 + xp2;
          const int a = (py + 1) * 448 + (px + 1) * 24 + oc;
          const __bf16 vh = (__bf16)v;
          s2b[a] = vh;
          s2b[8064 + a] = (__bf16)(v - (float)vh);
        }
  }
  bf16x8 Bf[18];
  #pragma unroll
  for (int f = 0; f < 18; ++f)
    Bf[f] = *(const bf16x8*)(b2p + f * 512 + lane * 8);
  __syncthreads();

  // ---- conv2 (R4-validated math, stride-448 addressing)
  float pooled2[8];
  {
    const unsigned short* s2 = (const unsigned short*)s2b;
    const int xm = lane & 15, yoff = (lane >> 4) & 1, kh = lane >> 5;
    f32x16v acc0, acc1;
    #pragma unroll
    for (int r = 0; r < 16; ++r) { acc0[r] = 0.f; acc1[r] = 0.f; }
    #pragma unroll
    for (int t = 0; t < 9; ++t) {
      const int ky = t / 3, kx = t % 3;
      const int col = (xm + kx) * 24 + kh * 8;
      const int row0 = (4 * w + yoff + ky) * 448 + col;
      const int row1 = row0 + 896;
      bf16x8 a0h = *(const bf16x8*)&s2[row0];
      bf16x8 a0l = *(const bf16x8*)&s2[8064 + row0];
      bf16x8 a1h = *(const bf16x8*)&s2[row1];
      bf16x8 a1l = *(const bf16x8*)&s2[8064 + row1];
      acc0 = __builtin_amdgcn_mfma_f32_32x32x16_bf16(a0h, Bf[t * 2],     acc0, 0, 0, 0);
      acc1 = __builtin_amdgcn_mfma_f32_32x32x16_bf16(a1h, Bf[t * 2],     acc1, 0, 0, 0);
      acc0 = __builtin_amdgcn_mfma_f32_32x32x16_bf16(a0h, Bf[t * 2 + 1], acc0, 0, 0, 0);
      acc1 = __builtin_amdgcn_mfma_f32_32x32x16_bf16(a1h, Bf[t * 2 + 1], acc1, 0, 0, 0);
      acc0 = __builtin_amdgcn_mfma_f32_32x32x16_bf16(a0l, Bf[t * 2],     acc0, 0, 0, 0);
      acc1 = __builtin_amdgcn_mfma_f32_32x32x16_bf16(a1l, Bf[t * 2],     acc1, 0, 0, 0);
    }
    #pragma unroll
    for (int i2 = 0; i2 < 2; ++i2) {
      const f32x16v& a = i2 ? acc1 : acc0;
      #pragma unroll
      for (int bq = 0; bq < 2; ++bq)
        #pragma unroll
        for (int rq = 0; rq < 2; ++rq) {
          const int r0 = bq * 4 + rq * 2;
          pooled2[i2 * 4 + bq * 2 + rq] =
              fmaxf(fmaxf(a[r0], a[r0 + 1]), fmaxf(a[r0 + 8], a[r0 + 9]));
        }
    }
  }
  __syncthreads();   // s2 dead; s3 may overwrite @0

  // ---- h2 -> s3 (row stride 448, part stride 4480)
  for (int i = tid; i < 72; i += 256) {
    int part = i >= 36, c = part ? i - 36 : i;
    int row, col;
    if (c < 10)      { row = 0;      col = c; }
    else if (c < 20) { row = 9;      col = c - 10; }
    else if (c < 28) { row = c - 19; col = 0; }
    else             { row = c - 27; col = 9; }
    unsigned long long* p = (unsigned long long*)&s3b[part * 4480 + row * 448 + col * 40];
    #pragma unroll
    for (int u = 0; u < 8; ++u) p[u] = 0ull;
  }
  {
    const int oc = lane & 31, hh = lane >> 5;
    const float bias = b2[oc];
    #pragma unroll
    for (int i2 = 0; i2 < 2; ++i2)
      #pragma unroll
      for (int bq = 0; bq < 2; ++bq)
        #pragma unroll
        for (int rq = 0; rq < 2; ++rq) {
          const float v = fmaxf(pooled2[i2 * 4 + bq * 2 + rq] + bias, 0.f);
          const int py = 2 * w + i2, px = 2 * hh + 4 * bq + rq;
          const int a = (py + 1) * 448 + (px + 1) * 40 + oc;
          const __bf16 vh = (__bf16)v;
          s3b[a] = vh;
          s3b[4480 + a] = (__bf16)(v - (float)vh);
        }
  }
  __syncthreads();

  // ---- conv3 (wave = nt = oc-tile), R4-validated math
  {
    const unsigned short* s3 = (const unsigned short*)s3b;
    const int nt = w;
    bf16x8 Bt[18];
    #pragma unroll
    for (int t = 0; t < 9; ++t) {
      Bt[t * 2]     = *(const bf16x8*)(b3p + (t * 8 + nt * 2) * 512 + lane * 8);
      Bt[t * 2 + 1] = *(const bf16x8*)(b3p + (t * 8 + nt * 2 + 1) * 512 + lane * 8);
    }
    const int m = lane & 15, quad = lane >> 4;
    const int xm = m & 7, yoff = m >> 3;
    f32x4 acc[4];
    #pragma unroll
    for (int mt = 0; mt < 4; ++mt)
      #pragma unroll
      for (int r = 0; r < 4; ++r) acc[mt][r] = 0.f;
    #pragma unroll
    for (int t = 0; t < 9; ++t) {
      const int ky = t / 3, kx = t % 3;
      #pragma unroll
      for (int mt = 0; mt < 4; ++mt) {
        const int ro = (2 * mt + yoff + ky) * 448 + (xm + kx) * 40 + quad * 8;
        bf16x8 ah = *(const bf16x8*)&s3[ro];
        bf16x8 al = *(const bf16x8*)&s3[4480 + ro];
        acc[mt] = __builtin_amdgcn_mfma_f32_16x16x32_bf16(ah, Bt[t * 2],     acc[mt], 0, 0, 0);
        acc[mt] = __builtin_amdgcn_mfma_f32_16x16x32_bf16(ah, Bt[t * 2 + 1], acc[mt], 0, 0, 0);
        acc[mt] = __builtin_amdgcn_mfma_f32_16x16x32_bf16(al, Bt[t * 2],     acc[mt], 0, 0, 0);
      }
    }
    // epilogue -> h3s (disjoint from s3; no sync needed before writes)
    const int ocl = lane & 15;
    #pragma unroll
    for (int mt = 0; mt < 4; ++mt) {
      float p0 = fmaxf(acc[mt][0], acc[mt][1]);
      float p1 = fmaxf(acc[mt][2], acc[mt][3]);
      p0 = fmaxf(p0, __shfl_xor(p0, 32, 64));
      p1 = fmaxf(p1, __shfl_xor(p1, 32, 64));
      if (quad < 2) {
        const int oc = nt * 16 + ocl;
        const float bias = b3[oc];
        const int base = oc * 16 + mt * 4 + (quad & 1) * 2;
        h3s[base]     = fmaxf(p0 + bias, 0.f);
        h3s[base + 1] = fmaxf(p1 + bias, 0.f);
      }
    }
  }
  __syncthreads();

  // ---- fc (wave 0)
  if (w == 0) {
    float hv[16];
    #pragma unroll
    for (int i = 0; i < 16; ++i) hv[i] = h3s[i * 64 + lane];
    #pragma unroll
    for (int j = 0; j < 10; ++j) {
      float dot = 0.f;
      #pragma unroll
      for (int i = 0; i < 16; ++i)
        dot = fmaf(hv[i], fcw[j * 1024 + i * 64 + lane], dot);
      #pragma unroll
      for (int s = 32; s > 0; s >>= 1) dot += __shfl_xor(dot, s, 64);
      if (lane == 0) out[img * 10 + j] = dot + fcb[j];
    }
  }
}

// -------------------------------------------------------------------- launch
extern "C" void kernel_launch(void* const* d_in, const int* in_sizes, int n_in,
                              void* d_out, int out_size, void* d_ws, size_t ws_size,
                              hipStream_t stream) {
  const float* x   = (const float*)d_in[0];
  const float* w1  = (const float*)d_in[1];
  const float* b1  = (const float*)d_in[2];
  const float* w2  = (const float*)d_in[3];
  const float* b2  = (const float*)d_in[4];
  const float* w3  = (const float*)d_in[5];
  const float* b3  = (const float*)d_in[6];
  const float* fcw = (const float*)d_in[7];
  const float* fcb = (const float*)d_in[8];
  __bf16* wsb = (__bf16*)d_ws;
  float* out = (float*)d_out;

  hipLaunchKernelGGL(pack_weights, dim3(188), dim3(256), 0, stream, w1, w2, w3, wsb);
  hipLaunchKernelGGL(cnn_fused, dim3(4096), dim3(256), 0, stream,
                     x, wsb, b1, b2, b3, fcw, fcb, out);
}